// Round 1
// baseline (755.389 us; speedup 1.0000x reference)
//
#include <hip/hip_runtime.h>
#include <math.h>

#define C   256
#define CR  64
#define B   32
#define HW  12544      // 112*112
#define HW4 3136       // HW / 4 (exact)

// ---------------------------------------------------------------------------
// Kernel 1: global average pool over H,W. One block per (b,c) plane.
// 8192 blocks x 256 threads; float4 loads -> wave64 shuffle reduce -> LDS.
// ---------------------------------------------------------------------------
__global__ __launch_bounds__(256) void gap_kernel(const float* __restrict__ x,
                                                  float* __restrict__ gap) {
    const int bc = blockIdx.x;
    const float4* xp = reinterpret_cast<const float4*>(x) + (size_t)bc * HW4;

    float s = 0.0f;
    for (int i = threadIdx.x; i < HW4; i += 256) {
        float4 v = xp[i];
        s += (v.x + v.y) + (v.z + v.w);
    }
    // wave-64 butterfly reduce
    #pragma unroll
    for (int off = 32; off > 0; off >>= 1)
        s += __shfl_down(s, off, 64);

    __shared__ float wsum[4];
    const int lane = threadIdx.x & 63;
    const int wave = threadIdx.x >> 6;
    if (lane == 0) wsum[wave] = s;
    __syncthreads();
    if (threadIdx.x == 0) {
        float t = (wsum[0] + wsum[1]) + (wsum[2] + wsum[3]);
        gap[bc] = t * (1.0f / (float)HW);
    }
}

// ---------------------------------------------------------------------------
// Kernel 2: per-sample MLP + sigmoid gate. One block per batch sample.
// gap row -> LDS; 64 threads compute hidden (relu); 256 threads compute attn.
// ---------------------------------------------------------------------------
__global__ __launch_bounds__(256) void mlp_kernel(const float* __restrict__ gap,
                                                  const float* __restrict__ w1,
                                                  const float* __restrict__ b1,
                                                  const float* __restrict__ w2,
                                                  const float* __restrict__ b2,
                                                  float* __restrict__ gate) {
    const int b = blockIdx.x;
    __shared__ float sg[C];
    __shared__ float sh[CR];

    sg[threadIdx.x] = gap[b * C + threadIdx.x];
    __syncthreads();

    if (threadIdx.x < CR) {
        const int o = threadIdx.x;
        float acc = b1[o];
        const float* wr = w1 + o * C;   // w1 is [CR, C] row-major
        #pragma unroll 8
        for (int c = 0; c < C; ++c) acc = fmaf(sg[c], wr[c], acc);
        sh[o] = fmaxf(acc, 0.0f);
    }
    __syncthreads();

    const int c = threadIdx.x;
    float acc = b2[c];
    const float* wr = w2 + c * CR;      // w2 is [C, CR] row-major
    #pragma unroll 8
    for (int o = 0; o < CR; ++o) acc = fmaf(sh[o], wr[o], acc);
    gate[b * C + c] = 1.0f / (1.0f + expf(-acc));
}

// ---------------------------------------------------------------------------
// Kernel 3: out = x * gate[b,c]. One block per (b,c) plane, float4 I/O.
// ---------------------------------------------------------------------------
__global__ __launch_bounds__(256) void scale_kernel(const float* __restrict__ x,
                                                    const float* __restrict__ gate,
                                                    float* __restrict__ out) {
    const int bc = blockIdx.x;
    const float g = gate[bc];
    const float4* xp = reinterpret_cast<const float4*>(x)   + (size_t)bc * HW4;
    float4*       op = reinterpret_cast<float4*>(out)       + (size_t)bc * HW4;

    for (int i = threadIdx.x; i < HW4; i += 256) {
        float4 v = xp[i];
        v.x *= g; v.y *= g; v.z *= g; v.w *= g;
        op[i] = v;
    }
}

extern "C" void kernel_launch(void* const* d_in, const int* in_sizes, int n_in,
                              void* d_out, int out_size, void* d_ws, size_t ws_size,
                              hipStream_t stream) {
    const float* x  = (const float*)d_in[0];
    const float* w1 = (const float*)d_in[1];
    const float* b1 = (const float*)d_in[2];
    const float* w2 = (const float*)d_in[3];
    const float* b2 = (const float*)d_in[4];
    float* out = (float*)d_out;

    float* gap  = (float*)d_ws;          // B*C floats
    float* gate = gap + B * C;           // B*C floats

    gap_kernel<<<B * C, 256, 0, stream>>>(x, gap);
    mlp_kernel<<<B, 256, 0, stream>>>(gap, w1, b1, w2, b2, gate);
    scale_kernel<<<B * C, 256, 0, stream>>>(x, gate, out);
}